// Round 19
// baseline (1487.537 us; speedup 1.0000x reference)
//
#include <hip/hip_runtime.h>
#include <math.h>

#define NN 50000
#define EE 800000
#define TT 6
#define SS (EE+NN)

__device__ __forceinline__ float lrelu(float x){ return x > 0.f ? x : 0.2f*x; }
__device__ __forceinline__ float eluf(float x){ return x > 0.f ? x : expm1f(x); }

// ---------------- CSR build ----------------
__global__ void k_init_counts(int* __restrict__ c){
  int i = blockIdx.x*256 + threadIdx.x;
  if (i < NN) c[i] = 1;
}

__global__ void k_hist(const int* __restrict__ dst, int* __restrict__ c){
  int i = blockIdx.x*256 + threadIdx.x;
  if (i < EE) atomicAdd(&c[dst[i]], 1);
}

__global__ void k_scanA(const int* __restrict__ cnt, int* __restrict__ excl,
                        int* __restrict__ bsum){
  __shared__ int sh[1024];
  int tid = threadIdx.x;
  int i = blockIdx.x*1024 + tid;
  int v = (i < NN) ? cnt[i] : 0;
  int x = v;
  sh[tid] = x; __syncthreads();
  for (int off = 1; off < 1024; off <<= 1){
    int y = (tid >= off) ? sh[tid - off] : 0;
    __syncthreads();
    x += y; sh[tid] = x; __syncthreads();
  }
  if (i < NN) excl[i] = x - v;
  if (tid == 1023) bsum[blockIdx.x] = x;
}

__global__ void k_scanB(int* __restrict__ bsum, int nb){
  if (threadIdx.x == 0){
    int run = 0;
    for (int b = 0; b < nb; ++b){ int t = bsum[b]; bsum[b] = run; run += t; }
  }
}

__global__ void k_scanC(const int* __restrict__ excl, const int* __restrict__ bsum,
                        int* __restrict__ rowptr, int* __restrict__ cursor){
  int i = blockIdx.x*1024 + threadIdx.x;
  if (i < NN){
    int v = excl[i] + bsum[blockIdx.x];
    rowptr[i] = v; cursor[i] = v;
  }
  if (i == 0) rowptr[NN] = SS;
}

__global__ void k_scatter(const int* __restrict__ ei, int* __restrict__ cursor,
                          int* __restrict__ csr, int* __restrict__ dstOf){
  int i = blockIdx.x*256 + threadIdx.x;
  if (i < EE){
    int d = ei[EE + i];
    int p = atomicAdd(&cursor[d], 1);
    csr[p] = ei[i];
    dstOf[p] = d;
  } else if (i < SS){
    int v = i - EE;
    int p = atomicAdd(&cursor[v], 1);
    csr[p] = v;
    dstOf[p] = v;
  }
}

// ---------------- weight preprocessing ----------------
__global__ void k_prep(const float* __restrict__ W1, const float* __restrict__ as1,
                       const float* __restrict__ ad1,
                       const float* __restrict__ W2, const float* __restrict__ as2,
                       const float* __restrict__ ad2,
                       const float* __restrict__ cw1, const float* __restrict__ cw2,
                       const float* __restrict__ lw1,
                       float* __restrict__ Was1, float* __restrict__ Wad1,
                       float* __restrict__ Wat2, float* __restrict__ Wb,
                       float4* __restrict__ wq1, float4* __restrict__ wq2,
                       float* __restrict__ lw1t){
  int tid = threadIdx.x;          // 256
  int k = tid >> 2, h = tid & 3;
  float s1 = 0.f, d1 = 0.f, s2 = 0.f, d2 = 0.f;
  for (int c = 0; c < 16; ++c){
    float w = W1[k*64 + h*16 + c];
    s1 += w * as1[h*16 + c];
    d1 += w * ad1[h*16 + c];
  }
  for (int c = 0; c < 64; ++c){
    float w = W2[k*256 + h*64 + c];
    s2 += w * as2[h*64 + c];
    d2 += w * ad2[h*64 + c];
  }
  Was1[k*4+h] = s1; Wad1[k*4+h] = d1;
  Wat2[k*8 + h] = s2; Wat2[k*8 + 4 + h] = d2;
  for (int idx = tid; idx < 256*64; idx += 256){
    int kf = idx >> 6, c = idx & 63;
    int hh = kf >> 6, kk = kf & 63;
    Wb[idx] = W2[kk*256 + hh*64 + c];
  }
  // conv weights [o][i][k] -> float4 at [i*64+o]  (i-major)
  for (int idx = tid; idx < 64*64; idx += 256){
    int i = idx >> 6, o = idx & 63;
    wq1[idx] = make_float4(cw1[o*192+i*3], cw1[o*192+i*3+1], cw1[o*192+i*3+2], 0.f);
    wq2[idx] = make_float4(cw2[o*192+i*3], cw2[o*192+i*3+1], cw2[o*192+i*3+2], 0.f);
  }
  // lw1 [k][32] -> lw1t [j][k]
  for (int idx = tid; idx < 32*64; idx += 256){
    int j = idx >> 6, kk = idx & 63;
    lw1t[idx] = lw1[kk*32 + j];
  }
}

// ---------------- layer-1 GEMM (N x 64 @ 64 x 64) + fused attention epilogue ----
__global__ __launch_bounds__(256) void k_gemm_att1(const float* __restrict__ A,
                            const float* __restrict__ W,
                            const float* __restrict__ Was, const float* __restrict__ Wad,
                            float* __restrict__ Xl, float* __restrict__ a_src,
                            float* __restrict__ a_dst){
  __shared__ float At[64][16];
  int tid = threadIdx.x;
  int r0 = blockIdx.x * 16;
  {
    const float4* A4 = (const float4*)(A + (size_t)r0*64);
    float4 v = A4[tid];
    int r = tid >> 4, k4 = (tid & 15) << 2;
    At[k4+0][r] = v.x; At[k4+1][r] = v.y;
    At[k4+2][r] = v.z; At[k4+3][r] = v.w;
  }
  __syncthreads();
  int col = tid & 63;
  int rbase = (tid >> 6) << 2;
  float acc0=0.f, acc1=0.f, acc2=0.f, acc3=0.f;
  for (int k = 0; k < 64; ++k){
    float w = W[k*64 + col];
    float4 a4 = *(const float4*)&At[k][rbase];
    acc0 += a4.x*w; acc1 += a4.y*w; acc2 += a4.z*w; acc3 += a4.w*w;
  }
  Xl[(size_t)(r0+rbase+0)*64 + col] = acc0;
  Xl[(size_t)(r0+rbase+1)*64 + col] = acc1;
  Xl[(size_t)(r0+rbase+2)*64 + col] = acc2;
  Xl[(size_t)(r0+rbase+3)*64 + col] = acc3;
  if (tid < 128){
    int r = tid >> 3, jx = tid & 7;
    int h = jx & 3;
    const float* Wv = (jx < 4) ? Was : Wad;
    float a = 0.f;
    for (int k = 0; k < 64; ++k) a += At[k][r] * Wv[k*4 + h];
    if (jx < 4) a_src[(r0 + r)*4 + h] = a;
    else        a_dst[(r0 + r)*4 + h] = a;
  }
}

// ---------------- per-edge coefficients, layer 1 (planar by head) ----------------
__global__ __launch_bounds__(256) void k_edge1(const int* __restrict__ csr,
                        const int* __restrict__ dstOf,
                        const float* __restrict__ a_src, const float* __restrict__ a_dst,
                        float* __restrict__ peh){
  int k = blockIdx.x*256 + threadIdx.x;
  if (k >= SS) return;
  int sn = csr[k], dn = dstOf[k];
  float4 as = ((const float4*)a_src)[sn];
  float4 ad = ((const float4*)a_dst)[dn];
  peh[k]                 = __expf(lrelu(as.x+ad.x));
  peh[(size_t)SS + k]    = __expf(lrelu(as.y+ad.y));
  peh[2*(size_t)SS + k]  = __expf(lrelu(as.z+ad.z));
  peh[3*(size_t)SS + k]  = __expf(lrelu(as.w+ad.w));
}

// ---------------- per-edge coefficients, layer 2 (float4 interleaved) ------------
__global__ __launch_bounds__(256) void k_edge2(const int* __restrict__ csr,
                        const int* __restrict__ dstOf,
                        const float* __restrict__ a_src, const float* __restrict__ a_dst,
                        float4* __restrict__ pe4){
  int k = blockIdx.x*256 + threadIdx.x;
  if (k >= SS) return;
  int sn = csr[k], dn = dstOf[k];
  float4 as = ((const float4*)a_src)[sn];
  float4 ad = ((const float4*)a_dst)[dn];
  pe4[k] = make_float4(__expf(lrelu(as.x+ad.x)), __expf(lrelu(as.y+ad.y)),
                       __expf(lrelu(as.z+ad.z)), __expf(lrelu(as.w+ad.w)));
}

// -------- layer 1 aggregation (1 wave/node, 4-edge, scalar coefs) + att2 --------
__global__ __launch_bounds__(256) void k_agg1(
                       const float* __restrict__ xl, const float* __restrict__ peh,
                       const float* __restrict__ b1, const float* __restrict__ Wat2,
                       const int* __restrict__ rowptr, const int* __restrict__ csr,
                       float* __restrict__ h1,
                       float* __restrict__ a_src2, float* __restrict__ a_dst2){
  int lane = threadIdx.x & 63;
  int wid  = __builtin_amdgcn_readfirstlane(threadIdx.x >> 6);
  int n = blockIdx.x*4 + wid;
  int h = lane >> 4;
  const float* __restrict__ ph = peh + (size_t)h*SS;
  int rs = rowptr[n], re = rowptr[n+1];
  float s = 0.f, acc = 0.f;
  int j = rs;
  for (; j + 4 <= re; j += 4){
    int sn0=csr[j], sn1=csr[j+1], sn2=csr[j+2], sn3=csr[j+3];
    float p0=ph[j], p1=ph[j+1], p2=ph[j+2], p3=ph[j+3];
    float x0=xl[(size_t)sn0*64+lane], x1=xl[(size_t)sn1*64+lane];
    float x2=xl[(size_t)sn2*64+lane], x3=xl[(size_t)sn3*64+lane];
    s += p0; acc += p0*x0;
    s += p1; acc += p1*x1;
    s += p2; acc += p2*x2;
    s += p3; acc += p3*x3;
  }
  for (; j < re; ++j){
    int sn = csr[j];
    float p = ph[j];
    float x = xl[(size_t)sn*64 + lane];
    s += p; acc += p*x;
  }
  float hv = eluf(acc/(s + 1e-16f) + b1[lane]);
  h1[(size_t)n*64 + lane] = hv;
  // layer-2 attention coefficients: p[j] = sum_k h1[n][k]*Wat2[k][j]
  float4 wA = ((const float4*)Wat2)[lane*2];
  float4 wB = ((const float4*)Wat2)[lane*2 + 1];
  float p[8];
  p[0]=hv*wA.x; p[1]=hv*wA.y; p[2]=hv*wA.z; p[3]=hv*wA.w;
  p[4]=hv*wB.x; p[5]=hv*wB.y; p[6]=hv*wB.z; p[7]=hv*wB.w;
#pragma unroll
  for (int off = 32; off >= 1; off >>= 1){
#pragma unroll
    for (int q = 0; q < 8; ++q) p[q] += __shfl_xor(p[q], off);
  }
  if (lane == 0){
    ((float4*)a_src2)[n] = make_float4(p[0],p[1],p[2],p[3]);
    ((float4*)a_dst2)[n] = make_float4(p[4],p[5],p[6],p[7]);
  }
}

// ---- layer 2 aggregation + FUSED output GEMM: wave holds agg row, LDS bounce ---
// After the edge loop, lane holds agg[n][h*64+lane] for h=0..3. Dump to LDS,
// then lane=col computes elu(0.25 * row @ Wb + b2) directly -> htb.
__global__ __launch_bounds__(256) void k_agg2out(
                       const float* __restrict__ h1, const float4* __restrict__ pe4,
                       const int* __restrict__ rowptr, const int* __restrict__ csr,
                       const float* __restrict__ Wb, const float* __restrict__ b2,
                       float* __restrict__ ht){
  __shared__ float R[4][256];
  int lane = threadIdx.x & 63;
  int wid  = __builtin_amdgcn_readfirstlane(threadIdx.x >> 6);
  int n = blockIdx.x*4 + wid;
  int rs = rowptr[n], re = rowptr[n+1];
  float s0=0.f,s1=0.f,s2=0.f,s3=0.f;
  float g0=0.f,g1=0.f,g2=0.f,g3=0.f;
  int j = rs;
  for (; j + 4 <= re; j += 4){
    int sa=csr[j], sb=csr[j+1], sc=csr[j+2], sd=csr[j+3];
    float4 pa = pe4[j];
    float4 pb = pe4[j+1];
    float4 pc = pe4[j+2];
    float4 pd = pe4[j+3];
    float xa = h1[(size_t)sa*64 + lane];
    float xb = h1[(size_t)sb*64 + lane];
    float xc = h1[(size_t)sc*64 + lane];
    float xd = h1[(size_t)sd*64 + lane];
    s0 += pa.x+pb.x+pc.x+pd.x; g0 += pa.x*xa + pb.x*xb + pc.x*xc + pd.x*xd;
    s1 += pa.y+pb.y+pc.y+pd.y; g1 += pa.y*xa + pb.y*xb + pc.y*xc + pd.y*xd;
    s2 += pa.z+pb.z+pc.z+pd.z; g2 += pa.z*xa + pb.z*xb + pc.z*xc + pd.z*xd;
    s3 += pa.w+pb.w+pc.w+pd.w; g3 += pa.w*xa + pb.w*xb + pc.w*xc + pd.w*xd;
  }
  for (; j < re; ++j){
    int sn = csr[j];
    float4 pv = pe4[j];
    float x = h1[(size_t)sn*64 + lane];
    s0 += pv.x; g0 += pv.x*x;
    s1 += pv.y; g1 += pv.y*x;
    s2 += pv.z; g2 += pv.z*x;
    s3 += pv.w; g3 += pv.w*x;
  }
  R[wid][lane      ] = g0/(s0 + 1e-16f);
  R[wid][ 64 + lane] = g1/(s1 + 1e-16f);
  R[wid][128 + lane] = g2/(s2 + 1e-16f);
  R[wid][192 + lane] = g3/(s3 + 1e-16f);
  __syncthreads();
  // row @ Wb: lane = output col; LDS reads are wave-broadcast; Wb coalesced/L1
  const float* __restrict__ Rw = R[wid];
  float acc = 0.f;
#pragma unroll 8
  for (int k = 0; k < 256; k += 4){
    float4 a = *(const float4*)&Rw[k];
    acc += a.x*Wb[(k  )*64 + lane] + a.y*Wb[(k+1)*64 + lane]
         + a.z*Wb[(k+2)*64 + lane] + a.w*Wb[(k+3)*64 + lane];
  }
  ht[(size_t)n*64 + lane] = eluf(0.25f*acc + b2[lane]);
}

// ---- fused conv1+conv2+pool: R13 geometry exactly (16 nodes/block, 26 KB) ------
// X[ch][t][nn] stride: ch*103 + t*17 + nn. Thread = (o-quad, node).
__global__ __launch_bounds__(256) void k_conv(const float* __restrict__ htb,
    const float4* __restrict__ wq1, const float* __restrict__ cb1,
    const float* __restrict__ g1,   const float* __restrict__ be1,
    const float4* __restrict__ wq2, const float* __restrict__ cb2,
    const float* __restrict__ g2,   const float* __restrict__ be2,
    float* __restrict__ pooledG){
  __shared__ float X[64*103];      // 26368 B
  int tid  = threadIdx.x;
  int lane = tid & 63;
  int w    = __builtin_amdgcn_readfirstlane(tid >> 6);
  int nn   = lane & 15;
  int oq   = lane >> 4;            // 0..3
  int n0 = blockIdx.x*16;          // 3125 blocks exactly
  int n  = n0 + nn;
  int ob = w*16 + oq*4;            // this thread's 4 output channels

  // stage htb[t][n][ch] -> X[ch*103 + t*17 + ns]
#pragma unroll
  for (int k = 0; k < 4; ++k){
    int p  = k*256 + tid;          // 1024 = 16 nodes x 64 ch
    int ch = p & 63, ns = p >> 6;
    float xv[6];
#pragma unroll
    for (int t = 0; t < 6; ++t) xv[t] = htb[((size_t)t*NN + n0 + ns)*64 + ch];
#pragma unroll
    for (int t = 0; t < 6; ++t) X[ch*103 + t*17 + ns] = xv[t];
  }
  __syncthreads();

  float acc[4][6];
  // ---- conv1 ----
#pragma unroll
  for (int q = 0; q < 4; ++q){
    float c = cb1[ob+q];
#pragma unroll
    for (int t = 0; t < 6; ++t) acc[q][t] = c;
  }
  for (int i = 0; i < 64; ++i){
    const float* xp = X + i*103 + nn;
    float x1 = xp[0], x2 = xp[17], x3 = xp[34];
    float x4 = xp[51], x5 = xp[68], x6 = xp[85];
#pragma unroll
    for (int q = 0; q < 4; ++q){
      float4 wv = wq1[(i<<6) + ob + q];
      acc[q][0] += wv.y*x1 + wv.z*x2;
      acc[q][1] += wv.x*x1 + wv.y*x2 + wv.z*x3;
      acc[q][2] += wv.x*x2 + wv.y*x3 + wv.z*x4;
      acc[q][3] += wv.x*x3 + wv.y*x4 + wv.z*x5;
      acc[q][4] += wv.x*x4 + wv.y*x5 + wv.z*x6;
      acc[q][5] += wv.x*x5 + wv.y*x6;
    }
  }
  __syncthreads();   // all reads of X done
#pragma unroll
  for (int q = 0; q < 4; ++q){
    float bns = g1[ob+q]*rsqrtf(1.f + 1e-5f), be = be1[ob+q];
    float* xp = X + (ob+q)*103 + nn;
#pragma unroll
    for (int t = 0; t < 6; ++t) xp[t*17] = fmaxf(acc[q][t]*bns + be, 0.f);
  }
  __syncthreads();

  // ---- conv2 + pool ----
#pragma unroll
  for (int q = 0; q < 4; ++q){
    float c = cb2[ob+q];
#pragma unroll
    for (int t = 0; t < 6; ++t) acc[q][t] = c;
  }
  for (int i = 0; i < 64; ++i){
    const float* xp = X + i*103 + nn;
    float x1 = xp[0], x2 = xp[17], x3 = xp[34];
    float x4 = xp[51], x5 = xp[68], x6 = xp[85];
#pragma unroll
    for (int q = 0; q < 4; ++q){
      float4 wv = wq2[(i<<6) + ob + q];
      acc[q][0] += wv.y*x1 + wv.z*x2;
      acc[q][1] += wv.x*x1 + wv.y*x2 + wv.z*x3;
      acc[q][2] += wv.x*x2 + wv.y*x3 + wv.z*x4;
      acc[q][3] += wv.x*x3 + wv.y*x4 + wv.z*x5;
      acc[q][4] += wv.x*x4 + wv.y*x5 + wv.z*x6;
      acc[q][5] += wv.x*x5 + wv.y*x6;
    }
  }
#pragma unroll
  for (int q = 0; q < 4; ++q){
    float bns = g2[ob+q]*rsqrtf(1.f + 1e-5f), be = be2[ob+q];
    float pooled = 0.f;
#pragma unroll
    for (int t = 0; t < 6; ++t) pooled += fmaxf(acc[q][t]*bns + be, 0.f);
    pooledG[(size_t)(ob+q)*NN + n] = pooled*(1.f/6.f);
  }
}

// ------------- MLP: lane = node; pooled row in regs; weights uniform -----------
__global__ __launch_bounds__(256) void k_mlp(const float* __restrict__ pooledG,
    const float* __restrict__ lw1t, const float* __restrict__ lb1,
    const float* __restrict__ lw2,  const float* __restrict__ lb2,
    float* __restrict__ out){
  int lane = threadIdx.x & 63;
  int w = __builtin_amdgcn_readfirstlane(threadIdx.x >> 6);
  int n = (blockIdx.x*4 + w)*64 + lane;
  int nc = (n < NN) ? n : (NN-1);
  float p[64];
#pragma unroll 16
  for (int o = 0; o < 64; ++o) p[o] = pooledG[(size_t)o*NN + nc];
  float po = 0.f;
  for (int j = 0; j < 32; ++j){
    float hj = lb1[j];
#pragma unroll 16
    for (int k = 0; k < 64; ++k) hj += p[k] * lw1t[j*64 + k];
    po += fmaxf(hj, 0.f) * lw2[j];
  }
  if (n < NN) out[n] = po + lb2[0];
}

// ---------------- launch ----------------
extern "C" void kernel_launch(void* const* d_in, const int* in_sizes, int n_in,
                              void* d_out, int out_size, void* d_ws, size_t ws_size,
                              hipStream_t stream) {
  const float* x_seq = (const float*)d_in[0];
  const int*   ei    = (const int*)  d_in[1];
  const float* W1  = (const float*)d_in[2];
  const float* as1 = (const float*)d_in[3];
  const float* ad1 = (const float*)d_in[4];
  const float* b1  = (const float*)d_in[5];
  const float* W2  = (const float*)d_in[6];
  const float* as2 = (const float*)d_in[7];
  const float* ad2 = (const float*)d_in[8];
  const float* b2  = (const float*)d_in[9];
  const float* cw1 = (const float*)d_in[10];
  const float* cb1 = (const float*)d_in[11];
  const float* g1  = (const float*)d_in[12];
  const float* be1 = (const float*)d_in[13];
  const float* cw2 = (const float*)d_in[14];
  const float* cb2 = (const float*)d_in[15];
  const float* g2  = (const float*)d_in[16];
  const float* be2 = (const float*)d_in[17];
  const float* lw1 = (const float*)d_in[18];
  const float* lb1 = (const float*)d_in[19];
  const float* lw2 = (const float*)d_in[20];
  const float* lb2 = (const float*)d_in[21];
  float* out = (float*)d_out;

  char* wp = (char*)d_ws;
  auto alloc = [&](size_t bytes) -> char* {
    char* p = wp; wp += (bytes + 255) & ~(size_t)255; return p;
  };
  int*   counts = (int*)  alloc(NN*sizeof(int));
  int*   excl   = (int*)  alloc(NN*sizeof(int));
  int*   bsum   = (int*)  alloc(64*sizeof(int));
  int*   rowptr = (int*)  alloc((NN+1)*sizeof(int));
  int*   cursor = (int*)  alloc(NN*sizeof(int));
  int*   csr    = (int*)  alloc((size_t)SS*sizeof(int));
  int*   dstOf  = (int*)  alloc((size_t)SS*sizeof(int));
  float* peh    = (float*)alloc((size_t)4*SS*sizeof(float));
  float4* pe4   = (float4*)alloc((size_t)SS*sizeof(float4));
  float* a_src1 = (float*)alloc((size_t)NN*4*sizeof(float));
  float* a_dst1 = (float*)alloc((size_t)NN*4*sizeof(float));
  float* a_src2 = (float*)alloc((size_t)NN*4*sizeof(float));
  float* a_dst2 = (float*)alloc((size_t)NN*4*sizeof(float));
  float* h1     = (float*)alloc((size_t)NN*64*sizeof(float));
  float* xl1    = (float*)alloc((size_t)NN*64*sizeof(float));
  float* htb    = (float*)alloc((size_t)TT*NN*64*sizeof(float));
  float* pooledG= (float*)alloc((size_t)64*NN*sizeof(float));
  float* Was1 = (float*)alloc(256*sizeof(float));
  float* Wad1 = (float*)alloc(256*sizeof(float));
  float* Wat2 = (float*)alloc(64*8*sizeof(float));
  float* Wb   = (float*)alloc(256*64*sizeof(float));
  float4* wq1 = (float4*)alloc(64*64*sizeof(float4));
  float4* wq2 = (float4*)alloc(64*64*sizeof(float4));
  float* lw1t = (float*)alloc(32*64*sizeof(float));

  const int NBSCAN = (NN + 1023)/1024;   // 49
  k_init_counts<<<(NN+255)/256, 256, 0, stream>>>(counts);
  k_hist<<<(EE+255)/256, 256, 0, stream>>>(ei + EE, counts);
  k_scanA<<<NBSCAN, 1024, 0, stream>>>(counts, excl, bsum);
  k_scanB<<<1, 64, 0, stream>>>(bsum, NBSCAN);
  k_scanC<<<NBSCAN, 1024, 0, stream>>>(excl, bsum, rowptr, cursor);
  k_scatter<<<(SS+255)/256, 256, 0, stream>>>(ei, cursor, csr, dstOf);
  k_prep<<<1, 256, 0, stream>>>(W1, as1, ad1, W2, as2, ad2, cw1, cw2, lw1,
                                Was1, Wad1, Wat2, Wb, wq1, wq2, lw1t);

  const int NEDGE = (SS + 255)/256;
  for (int t = 0; t < TT; ++t){
    const float* xt = x_seq + (size_t)t*NN*64;
    k_gemm_att1<<<NN/16, 256, 0, stream>>>(xt, W1, Was1, Wad1, xl1, a_src1, a_dst1);
    k_edge1<<<NEDGE, 256, 0, stream>>>(csr, dstOf, a_src1, a_dst1, peh);
    k_agg1<<<NN/4, 256, 0, stream>>>(xl1, peh, b1, Wat2, rowptr, csr,
                                     h1, a_src2, a_dst2);
    k_edge2<<<NEDGE, 256, 0, stream>>>(csr, dstOf, a_src2, a_dst2, pe4);
    k_agg2out<<<NN/4, 256, 0, stream>>>(h1, pe4, rowptr, csr, Wb, b2,
                                        htb + (size_t)t*NN*64);
  }
  k_conv<<<NN/16, 256, 0, stream>>>(htb, wq1, cb1, g1, be1, wq2, cb2, g2, be2,
                                    pooledG);
  k_mlp<<<(NN+255)/256, 256, 0, stream>>>(pooledG, lw1t, lb1, lw2, lb2, out);
}

// Round 20
// 1331.677 us; speedup vs baseline: 1.1170x; 1.1170x over previous
//
#include <hip/hip_runtime.h>
#include <math.h>

#define NN 50000
#define EE 800000
#define TT 6
#define SS (EE+NN)

__device__ __forceinline__ float lrelu(float x){ return x > 0.f ? x : 0.2f*x; }
__device__ __forceinline__ float eluf(float x){ return x > 0.f ? x : expm1f(x); }

// ---------------- CSR build ----------------
__global__ void k_init_counts(int* __restrict__ c){
  int i = blockIdx.x*256 + threadIdx.x;
  if (i < NN) c[i] = 1;
}

__global__ void k_hist(const int* __restrict__ dst, int* __restrict__ c){
  int i = blockIdx.x*256 + threadIdx.x;
  if (i < EE) atomicAdd(&c[dst[i]], 1);
}

__global__ void k_scanA(const int* __restrict__ cnt, int* __restrict__ excl,
                        int* __restrict__ bsum){
  __shared__ int sh[1024];
  int tid = threadIdx.x;
  int i = blockIdx.x*1024 + tid;
  int v = (i < NN) ? cnt[i] : 0;
  int x = v;
  sh[tid] = x; __syncthreads();
  for (int off = 1; off < 1024; off <<= 1){
    int y = (tid >= off) ? sh[tid - off] : 0;
    __syncthreads();
    x += y; sh[tid] = x; __syncthreads();
  }
  if (i < NN) excl[i] = x - v;
  if (tid == 1023) bsum[blockIdx.x] = x;
}

__global__ void k_scanB(int* __restrict__ bsum, int nb){
  if (threadIdx.x == 0){
    int run = 0;
    for (int b = 0; b < nb; ++b){ int t = bsum[b]; bsum[b] = run; run += t; }
  }
}

__global__ void k_scanC(const int* __restrict__ excl, const int* __restrict__ bsum,
                        int* __restrict__ rowptr, int* __restrict__ cursor){
  int i = blockIdx.x*1024 + threadIdx.x;
  if (i < NN){
    int v = excl[i] + bsum[blockIdx.x];
    rowptr[i] = v; cursor[i] = v;
  }
  if (i == 0) rowptr[NN] = SS;
}

__global__ void k_scatter(const int* __restrict__ ei, int* __restrict__ cursor,
                          int* __restrict__ csr, int* __restrict__ dstOf){
  int i = blockIdx.x*256 + threadIdx.x;
  if (i < EE){
    int d = ei[EE + i];
    int p = atomicAdd(&cursor[d], 1);
    csr[p] = ei[i];
    dstOf[p] = d;
  } else if (i < SS){
    int v = i - EE;
    int p = atomicAdd(&cursor[v], 1);
    csr[p] = v;
    dstOf[p] = v;
  }
}

// ---------------- weight preprocessing ----------------
__global__ void k_prep(const float* __restrict__ W1, const float* __restrict__ as1,
                       const float* __restrict__ ad1,
                       const float* __restrict__ W2, const float* __restrict__ as2,
                       const float* __restrict__ ad2,
                       const float* __restrict__ cw1, const float* __restrict__ cw2,
                       const float* __restrict__ lw1,
                       float* __restrict__ Was1, float* __restrict__ Wad1,
                       float* __restrict__ Wat2, float* __restrict__ Wb,
                       float4* __restrict__ wq1, float4* __restrict__ wq2,
                       float* __restrict__ lw1t){
  int tid = threadIdx.x;          // 256
  int k = tid >> 2, h = tid & 3;
  float s1 = 0.f, d1 = 0.f, s2 = 0.f, d2 = 0.f;
  for (int c = 0; c < 16; ++c){
    float w = W1[k*64 + h*16 + c];
    s1 += w * as1[h*16 + c];
    d1 += w * ad1[h*16 + c];
  }
  for (int c = 0; c < 64; ++c){
    float w = W2[k*256 + h*64 + c];
    s2 += w * as2[h*64 + c];
    d2 += w * ad2[h*64 + c];
  }
  Was1[k*4+h] = s1; Wad1[k*4+h] = d1;
  Wat2[k*8 + h] = s2; Wat2[k*8 + 4 + h] = d2;
  for (int idx = tid; idx < 256*64; idx += 256){
    int kf = idx >> 6, c = idx & 63;
    int hh = kf >> 6, kk = kf & 63;
    Wb[idx] = W2[kk*256 + hh*64 + c];
  }
  // conv weights [o][i][k] -> float4 at [i*64+o]  (i-major)
  for (int idx = tid; idx < 64*64; idx += 256){
    int i = idx >> 6, o = idx & 63;
    wq1[idx] = make_float4(cw1[o*192+i*3], cw1[o*192+i*3+1], cw1[o*192+i*3+2], 0.f);
    wq2[idx] = make_float4(cw2[o*192+i*3], cw2[o*192+i*3+1], cw2[o*192+i*3+2], 0.f);
  }
  // lw1 [k][32] -> lw1t [j][k]
  for (int idx = tid; idx < 32*64; idx += 256){
    int j = idx >> 6, kk = idx & 63;
    lw1t[idx] = lw1[kk*32 + j];
  }
}

// ---------------- layer-1 GEMM (N x 64 @ 64 x 64) + fused attention epilogue ----
__global__ __launch_bounds__(256) void k_gemm_att1(const float* __restrict__ A,
                            const float* __restrict__ W,
                            const float* __restrict__ Was, const float* __restrict__ Wad,
                            float* __restrict__ Xl, float* __restrict__ a_src,
                            float* __restrict__ a_dst){
  __shared__ float At[64][16];
  int tid = threadIdx.x;
  int r0 = blockIdx.x * 16;
  {
    const float4* A4 = (const float4*)(A + (size_t)r0*64);
    float4 v = A4[tid];
    int r = tid >> 4, k4 = (tid & 15) << 2;
    At[k4+0][r] = v.x; At[k4+1][r] = v.y;
    At[k4+2][r] = v.z; At[k4+3][r] = v.w;
  }
  __syncthreads();
  int col = tid & 63;
  int rbase = (tid >> 6) << 2;
  float acc0=0.f, acc1=0.f, acc2=0.f, acc3=0.f;
  for (int k = 0; k < 64; ++k){
    float w = W[k*64 + col];
    float4 a4 = *(const float4*)&At[k][rbase];
    acc0 += a4.x*w; acc1 += a4.y*w; acc2 += a4.z*w; acc3 += a4.w*w;
  }
  Xl[(size_t)(r0+rbase+0)*64 + col] = acc0;
  Xl[(size_t)(r0+rbase+1)*64 + col] = acc1;
  Xl[(size_t)(r0+rbase+2)*64 + col] = acc2;
  Xl[(size_t)(r0+rbase+3)*64 + col] = acc3;
  if (tid < 128){
    int r = tid >> 3, jx = tid & 7;
    int h = jx & 3;
    const float* Wv = (jx < 4) ? Was : Wad;
    float a = 0.f;
    for (int k = 0; k < 64; ++k) a += At[k][r] * Wv[k*4 + h];
    if (jx < 4) a_src[(r0 + r)*4 + h] = a;
    else        a_dst[(r0 + r)*4 + h] = a;
  }
}

// ---------------- per-edge coefficients, layer 1 (planar by head) ----------------
__global__ __launch_bounds__(256) void k_edge1(const int* __restrict__ csr,
                        const int* __restrict__ dstOf,
                        const float* __restrict__ a_src, const float* __restrict__ a_dst,
                        float* __restrict__ peh){
  int k = blockIdx.x*256 + threadIdx.x;
  if (k >= SS) return;
  int sn = csr[k], dn = dstOf[k];
  float4 as = ((const float4*)a_src)[sn];
  float4 ad = ((const float4*)a_dst)[dn];
  peh[k]                 = __expf(lrelu(as.x+ad.x));
  peh[(size_t)SS + k]    = __expf(lrelu(as.y+ad.y));
  peh[2*(size_t)SS + k]  = __expf(lrelu(as.z+ad.z));
  peh[3*(size_t)SS + k]  = __expf(lrelu(as.w+ad.w));
}

// ---------------- per-edge coefficients, layer 2 (float4 interleaved) ------------
__global__ __launch_bounds__(256) void k_edge2(const int* __restrict__ csr,
                        const int* __restrict__ dstOf,
                        const float* __restrict__ a_src, const float* __restrict__ a_dst,
                        float4* __restrict__ pe4){
  int k = blockIdx.x*256 + threadIdx.x;
  if (k >= SS) return;
  int sn = csr[k], dn = dstOf[k];
  float4 as = ((const float4*)a_src)[sn];
  float4 ad = ((const float4*)a_dst)[dn];
  pe4[k] = make_float4(__expf(lrelu(as.x+ad.x)), __expf(lrelu(as.y+ad.y)),
                       __expf(lrelu(as.z+ad.z)), __expf(lrelu(as.w+ad.w)));
}

// -------- layer 1 aggregation (1 wave/node, 4-edge, scalar coefs) + att2 --------
__global__ __launch_bounds__(256) void k_agg1(
                       const float* __restrict__ xl, const float* __restrict__ peh,
                       const float* __restrict__ b1, const float* __restrict__ Wat2,
                       const int* __restrict__ rowptr, const int* __restrict__ csr,
                       float* __restrict__ h1,
                       float* __restrict__ a_src2, float* __restrict__ a_dst2){
  int lane = threadIdx.x & 63;
  int wid  = __builtin_amdgcn_readfirstlane(threadIdx.x >> 6);
  int n = blockIdx.x*4 + wid;
  int h = lane >> 4;
  const float* __restrict__ ph = peh + (size_t)h*SS;
  int rs = rowptr[n], re = rowptr[n+1];
  float s = 0.f, acc = 0.f;
  int j = rs;
  for (; j + 4 <= re; j += 4){
    int sn0=csr[j], sn1=csr[j+1], sn2=csr[j+2], sn3=csr[j+3];
    float p0=ph[j], p1=ph[j+1], p2=ph[j+2], p3=ph[j+3];
    float x0=xl[(size_t)sn0*64+lane], x1=xl[(size_t)sn1*64+lane];
    float x2=xl[(size_t)sn2*64+lane], x3=xl[(size_t)sn3*64+lane];
    s += p0; acc += p0*x0;
    s += p1; acc += p1*x1;
    s += p2; acc += p2*x2;
    s += p3; acc += p3*x3;
  }
  for (; j < re; ++j){
    int sn = csr[j];
    float p = ph[j];
    float x = xl[(size_t)sn*64 + lane];
    s += p; acc += p*x;
  }
  float hv = eluf(acc/(s + 1e-16f) + b1[lane]);
  h1[(size_t)n*64 + lane] = hv;
  // layer-2 attention coefficients: p[j] = sum_k h1[n][k]*Wat2[k][j]
  float4 wA = ((const float4*)Wat2)[lane*2];
  float4 wB = ((const float4*)Wat2)[lane*2 + 1];
  float p[8];
  p[0]=hv*wA.x; p[1]=hv*wA.y; p[2]=hv*wA.z; p[3]=hv*wA.w;
  p[4]=hv*wB.x; p[5]=hv*wB.y; p[6]=hv*wB.z; p[7]=hv*wB.w;
#pragma unroll
  for (int off = 32; off >= 1; off >>= 1){
#pragma unroll
    for (int q = 0; q < 8; ++q) p[q] += __shfl_xor(p[q], off);
  }
  if (lane == 0){
    ((float4*)a_src2)[n] = make_float4(p[0],p[1],p[2],p[3]);
    ((float4*)a_dst2)[n] = make_float4(p[4],p[5],p[6],p[7]);
  }
}

// -------- layer 2 aggregation over h1 (commuted past W2), 4-edge scalar coefs ---
__global__ __launch_bounds__(256) void k_agg2(
                       const float* __restrict__ h1, const float4* __restrict__ pe4,
                       const int* __restrict__ rowptr, const int* __restrict__ csr,
                       float* __restrict__ agg){
  int lane = threadIdx.x & 63;
  int wid  = __builtin_amdgcn_readfirstlane(threadIdx.x >> 6);
  int n = blockIdx.x*4 + wid;
  int rs = rowptr[n], re = rowptr[n+1];
  float s0=0.f,s1=0.f,s2=0.f,s3=0.f;
  float g0=0.f,g1=0.f,g2=0.f,g3=0.f;
  int j = rs;
  for (; j + 4 <= re; j += 4){
    int sa=csr[j], sb=csr[j+1], sc=csr[j+2], sd=csr[j+3];
    float4 pa = pe4[j];
    float4 pb = pe4[j+1];
    float4 pc = pe4[j+2];
    float4 pd = pe4[j+3];
    float xa = h1[(size_t)sa*64 + lane];
    float xb = h1[(size_t)sb*64 + lane];
    float xc = h1[(size_t)sc*64 + lane];
    float xd = h1[(size_t)sd*64 + lane];
    s0 += pa.x+pb.x+pc.x+pd.x; g0 += pa.x*xa + pb.x*xb + pc.x*xc + pd.x*xd;
    s1 += pa.y+pb.y+pc.y+pd.y; g1 += pa.y*xa + pb.y*xb + pc.y*xc + pd.y*xd;
    s2 += pa.z+pb.z+pc.z+pd.z; g2 += pa.z*xa + pb.z*xb + pc.z*xc + pd.z*xd;
    s3 += pa.w+pb.w+pc.w+pd.w; g3 += pa.w*xa + pb.w*xb + pc.w*xc + pd.w*xd;
  }
  for (; j < re; ++j){
    int sn = csr[j];
    float4 pv = pe4[j];
    float x = h1[(size_t)sn*64 + lane];
    s0 += pv.x; g0 += pv.x*x;
    s1 += pv.y; g1 += pv.y*x;
    s2 += pv.z; g2 += pv.z*x;
    s3 += pv.w; g3 += pv.w*x;
  }
  size_t base = (size_t)n*256 + lane;
  agg[base      ] = g0/(s0 + 1e-16f);
  agg[base +  64] = g1/(s1 + 1e-16f);
  agg[base + 128] = g2/(s2 + 1e-16f);
  agg[base + 192] = g3/(s3 + 1e-16f);
}

// ---- layer-2 output GEMM: lane = row, wave-uniform weights (s_load) ------------
__global__ __launch_bounds__(256) void k_out2(const float* __restrict__ agg,
                                              const float* __restrict__ Wb,
                                              const float* __restrict__ b2,
                                              float* __restrict__ ht){
  __shared__ float A[64*257];   // reused as O[64][65] for output transpose
  int tid = threadIdx.x;
  int lane = tid & 63;
  int w = __builtin_amdgcn_readfirstlane(tid >> 6);
  int r0 = blockIdx.x * 64;
  for (int jj = 0; jj < 64; ++jj){
    int m = jj*256 + tid;        // 16384 = 64 rows x 256 k
    int row = m >> 8, k = m & 255;
    int rsrc = r0 + row; if (rsrc >= NN) rsrc = NN-1;
    A[row*257 + k] = agg[(size_t)rsrc*256 + k];
  }
  __syncthreads();
  const float* __restrict__ Wbw = Wb + w*16;
  float acc[16];
#pragma unroll
  for (int jq = 0; jq < 16; ++jq) acc[jq] = 0.f;
  const float* Ar = A + lane*257;
#pragma unroll 8
  for (int k = 0; k < 256; ++k){
    float a = Ar[k];
#pragma unroll
    for (int jq = 0; jq < 16; ++jq) acc[jq] += a * Wbw[(k<<6) + jq];
  }
  __syncthreads();
#pragma unroll
  for (int jq = 0; jq < 16; ++jq){
    int c = w*16 + jq;
    A[lane*65 + c] = eluf(0.25f*acc[jq] + b2[c]);
  }
  __syncthreads();
  for (int jj = 0; jj < 16; ++jj){
    int m = jj*256 + tid;        // 4096 = 64 rows x 64 cols
    int row = m >> 6, c = m & 63;
    int rdst = r0 + row;
    if (rdst < NN) ht[(size_t)rdst*64 + c] = A[row*65 + c];
  }
}

// ---- fused conv1+conv2+pool+MLP: R13 conv geometry, MLP in dead X LDS ----------
// X[ch][t][nn] stride: ch*103 + t*17 + nn. Thread = (o-quad, node).
// After conv2, pooled values go to X[0..1087] as P[k][node] (stride 17);
// MLP partials to X[1200..1455] as O2[g][node]; final sum by first 16 threads.
__global__ __launch_bounds__(256) void k_conv(const float* __restrict__ htb,
    const float4* __restrict__ wq1, const float* __restrict__ cb1,
    const float* __restrict__ g1,   const float* __restrict__ be1,
    const float4* __restrict__ wq2, const float* __restrict__ cb2,
    const float* __restrict__ g2,   const float* __restrict__ be2,
    const float* __restrict__ lw1t, const float* __restrict__ lb1,
    const float* __restrict__ lw2,  const float* __restrict__ lb2,
    float* __restrict__ out){
  __shared__ float X[64*103];      // 26368 B
  int tid  = threadIdx.x;
  int lane = tid & 63;
  int w    = __builtin_amdgcn_readfirstlane(tid >> 6);
  int nn   = lane & 15;
  int oq   = lane >> 4;            // 0..3
  int n0 = blockIdx.x*16;          // 3125 blocks exactly
  int ob = w*16 + oq*4;            // this thread's 4 output channels

  // stage htb[t][n][ch] -> X[ch*103 + t*17 + ns]
#pragma unroll
  for (int k = 0; k < 4; ++k){
    int p  = k*256 + tid;          // 1024 = 16 nodes x 64 ch
    int ch = p & 63, ns = p >> 6;
    float xv[6];
#pragma unroll
    for (int t = 0; t < 6; ++t) xv[t] = htb[((size_t)t*NN + n0 + ns)*64 + ch];
#pragma unroll
    for (int t = 0; t < 6; ++t) X[ch*103 + t*17 + ns] = xv[t];
  }
  __syncthreads();

  float acc[4][6];
  // ---- conv1 ----
#pragma unroll
  for (int q = 0; q < 4; ++q){
    float c = cb1[ob+q];
#pragma unroll
    for (int t = 0; t < 6; ++t) acc[q][t] = c;
  }
  for (int i = 0; i < 64; ++i){
    const float* xp = X + i*103 + nn;
    float x1 = xp[0], x2 = xp[17], x3 = xp[34];
    float x4 = xp[51], x5 = xp[68], x6 = xp[85];
#pragma unroll
    for (int q = 0; q < 4; ++q){
      float4 wv = wq1[(i<<6) + ob + q];
      acc[q][0] += wv.y*x1 + wv.z*x2;
      acc[q][1] += wv.x*x1 + wv.y*x2 + wv.z*x3;
      acc[q][2] += wv.x*x2 + wv.y*x3 + wv.z*x4;
      acc[q][3] += wv.x*x3 + wv.y*x4 + wv.z*x5;
      acc[q][4] += wv.x*x4 + wv.y*x5 + wv.z*x6;
      acc[q][5] += wv.x*x5 + wv.y*x6;
    }
  }
  __syncthreads();   // all reads of X done
#pragma unroll
  for (int q = 0; q < 4; ++q){
    float bns = g1[ob+q]*rsqrtf(1.f + 1e-5f), be = be1[ob+q];
    float* xp = X + (ob+q)*103 + nn;
#pragma unroll
    for (int t = 0; t < 6; ++t) xp[t*17] = fmaxf(acc[q][t]*bns + be, 0.f);
  }
  __syncthreads();

  // ---- conv2 + pool ----
#pragma unroll
  for (int q = 0; q < 4; ++q){
    float c = cb2[ob+q];
#pragma unroll
    for (int t = 0; t < 6; ++t) acc[q][t] = c;
  }
  for (int i = 0; i < 64; ++i){
    const float* xp = X + i*103 + nn;
    float x1 = xp[0], x2 = xp[17], x3 = xp[34];
    float x4 = xp[51], x5 = xp[68], x6 = xp[85];
#pragma unroll
    for (int q = 0; q < 4; ++q){
      float4 wv = wq2[(i<<6) + ob + q];
      acc[q][0] += wv.y*x1 + wv.z*x2;
      acc[q][1] += wv.x*x1 + wv.y*x2 + wv.z*x3;
      acc[q][2] += wv.x*x2 + wv.y*x3 + wv.z*x4;
      acc[q][3] += wv.x*x3 + wv.y*x4 + wv.z*x5;
      acc[q][4] += wv.x*x4 + wv.y*x5 + wv.z*x6;
      acc[q][5] += wv.x*x5 + wv.y*x6;
    }
  }
  __syncthreads();   // all conv2 reads of X done; X now dead -> reuse for P/O2
  // P[k][node] at X[k*17 + node], k = channel
#pragma unroll
  for (int q = 0; q < 4; ++q){
    float bns = g2[ob+q]*rsqrtf(1.f + 1e-5f), be = be2[ob+q];
    float pooled = 0.f;
#pragma unroll
    for (int t = 0; t < 6; ++t) pooled += fmaxf(acc[q][t]*bns + be, 0.f);
    X[(ob+q)*17 + nn] = pooled*(1.f/6.f);
  }
  __syncthreads();

  // ---- MLP: thread = (node nn, j-group g); g covers j = 2g, 2g+1 ----
  {
    int g = w*4 + oq;               // 0..15
    int j0 = g*2, j1 = g*2 + 1;
    float h0 = lb1[j0], h1v = lb1[j1];
    const float* lwa = lw1t + j0*64;
    const float* lwb = lw1t + j1*64;
#pragma unroll 8
    for (int k = 0; k < 64; ++k){
      float pk = X[k*17 + nn];
      h0  += pk * lwa[k];
      h1v += pk * lwb[k];
    }
    float po = fmaxf(h0, 0.f)*lw2[j0] + fmaxf(h1v, 0.f)*lw2[j1];
    X[1200 + g*16 + nn] = po;       // O2[g][node]
  }
  __syncthreads();
  if (tid < 16){
    float r = lb2[0];
#pragma unroll
    for (int g = 0; g < 16; ++g) r += X[1200 + g*16 + tid];
    out[n0 + tid] = r;
  }
}

// ---------------- launch ----------------
extern "C" void kernel_launch(void* const* d_in, const int* in_sizes, int n_in,
                              void* d_out, int out_size, void* d_ws, size_t ws_size,
                              hipStream_t stream) {
  const float* x_seq = (const float*)d_in[0];
  const int*   ei    = (const int*)  d_in[1];
  const float* W1  = (const float*)d_in[2];
  const float* as1 = (const float*)d_in[3];
  const float* ad1 = (const float*)d_in[4];
  const float* b1  = (const float*)d_in[5];
  const float* W2  = (const float*)d_in[6];
  const float* as2 = (const float*)d_in[7];
  const float* ad2 = (const float*)d_in[8];
  const float* b2  = (const float*)d_in[9];
  const float* cw1 = (const float*)d_in[10];
  const float* cb1 = (const float*)d_in[11];
  const float* g1  = (const float*)d_in[12];
  const float* be1 = (const float*)d_in[13];
  const float* cw2 = (const float*)d_in[14];
  const float* cb2 = (const float*)d_in[15];
  const float* g2  = (const float*)d_in[16];
  const float* be2 = (const float*)d_in[17];
  const float* lw1 = (const float*)d_in[18];
  const float* lb1 = (const float*)d_in[19];
  const float* lw2 = (const float*)d_in[20];
  const float* lb2 = (const float*)d_in[21];
  float* out = (float*)d_out;

  char* wp = (char*)d_ws;
  auto alloc = [&](size_t bytes) -> char* {
    char* p = wp; wp += (bytes + 255) & ~(size_t)255; return p;
  };
  int*   counts = (int*)  alloc(NN*sizeof(int));
  int*   excl   = (int*)  alloc(NN*sizeof(int));
  int*   bsum   = (int*)  alloc(64*sizeof(int));
  int*   rowptr = (int*)  alloc((NN+1)*sizeof(int));
  int*   cursor = (int*)  alloc(NN*sizeof(int));
  int*   csr    = (int*)  alloc((size_t)SS*sizeof(int));
  int*   dstOf  = (int*)  alloc((size_t)SS*sizeof(int));
  float* peh    = (float*)alloc((size_t)4*SS*sizeof(float));
  float4* pe4   = (float4*)alloc((size_t)SS*sizeof(float4));
  float* a_src1 = (float*)alloc((size_t)NN*4*sizeof(float));
  float* a_dst1 = (float*)alloc((size_t)NN*4*sizeof(float));
  float* a_src2 = (float*)alloc((size_t)NN*4*sizeof(float));
  float* a_dst2 = (float*)alloc((size_t)NN*4*sizeof(float));
  float* h1     = (float*)alloc((size_t)NN*64*sizeof(float));
  float* agg    = (float*)alloc((size_t)NN*256*sizeof(float));
  float* xl1    = agg;                 // layer-1 features (dead before agg write)
  float* htb    = (float*)alloc((size_t)TT*NN*64*sizeof(float));
  float* Was1 = (float*)alloc(256*sizeof(float));
  float* Wad1 = (float*)alloc(256*sizeof(float));
  float* Wat2 = (float*)alloc(64*8*sizeof(float));
  float* Wb   = (float*)alloc(256*64*sizeof(float));
  float4* wq1 = (float4*)alloc(64*64*sizeof(float4));
  float4* wq2 = (float4*)alloc(64*64*sizeof(float4));
  float* lw1t = (float*)alloc(32*64*sizeof(float));

  const int NBSCAN = (NN + 1023)/1024;   // 49
  k_init_counts<<<(NN+255)/256, 256, 0, stream>>>(counts);
  k_hist<<<(EE+255)/256, 256, 0, stream>>>(ei + EE, counts);
  k_scanA<<<NBSCAN, 1024, 0, stream>>>(counts, excl, bsum);
  k_scanB<<<1, 64, 0, stream>>>(bsum, NBSCAN);
  k_scanC<<<NBSCAN, 1024, 0, stream>>>(excl, bsum, rowptr, cursor);
  k_scatter<<<(SS+255)/256, 256, 0, stream>>>(ei, cursor, csr, dstOf);
  k_prep<<<1, 256, 0, stream>>>(W1, as1, ad1, W2, as2, ad2, cw1, cw2, lw1,
                                Was1, Wad1, Wat2, Wb, wq1, wq2, lw1t);

  const int NEDGE = (SS + 255)/256;
  const int NOUT2 = (NN + 63)/64;   // 782
  for (int t = 0; t < TT; ++t){
    const float* xt = x_seq + (size_t)t*NN*64;
    k_gemm_att1<<<NN/16, 256, 0, stream>>>(xt, W1, Was1, Wad1, xl1, a_src1, a_dst1);
    k_edge1<<<NEDGE, 256, 0, stream>>>(csr, dstOf, a_src1, a_dst1, peh);
    k_agg1<<<NN/4, 256, 0, stream>>>(xl1, peh, b1, Wat2, rowptr, csr,
                                     h1, a_src2, a_dst2);
    k_edge2<<<NEDGE, 256, 0, stream>>>(csr, dstOf, a_src2, a_dst2, pe4);
    k_agg2<<<NN/4, 256, 0, stream>>>(h1, pe4, rowptr, csr, agg);
    k_out2<<<NOUT2, 256, 0, stream>>>(agg, Wb, b2, htb + (size_t)t*NN*64);
  }
  k_conv<<<NN/16, 256, 0, stream>>>(htb, wq1, cb1, g1, be1, wq2, cb2, g2, be2,
                                    lw1t, lb1, lw2, lb2, out);
}